// Round 1
// baseline (746.447 us; speedup 1.0000x reference)
//
#include <hip/hip_runtime.h>

// DIN attention pooling, MI355X.
// Structure:
//   P1 wfrag_build : W1 seq-rows (K=256 reordered) -> bf16 MFMA-B-fragment layout in ws
//   P2 base_build  : base[b,h] = b1 + item_emb@W1[0:128] + cat_emb@W1[256:320]  (s-invariant)
//   main din_main  : per b: 4 s-chunks of 64 rows:
//                      stage seq feats fp32->bf16 LDS (plain [s][k], pitch 264 shorts),
//                      MFMA 16x16x32 bf16 h = A@Wseq (+base), silu, dot W2 (shfl reduce),
//                      sigmoid*mask -> raw score; accumulate UNNORMALIZED weighted sums
//                      from the same LDS tile; normalize by sum(score)+1e-8 at the end.
// Roofline: 422 MB input read -> ~67us HBM floor; 53.7 GFLOP bf16 MFMA hides under it.

#define Bsz  2048
#define Ssz  200
#define DI   128
#define DC   64
#define DT   32
#define DBh  32
#define HID  256
#define DOUT 192
#define AP   264   // LDS A row pitch in shorts (528 B: 16B-aligned, bank-skewed)

using short8  = __attribute__((ext_vector_type(8))) short;
using floatx4 = __attribute__((ext_vector_type(4))) float;

__device__ __forceinline__ short f2bf(float x) {
  unsigned u = __builtin_bit_cast(unsigned, x);
  u = (u + 0x7FFFu + ((u >> 16) & 1u)) >> 16;   // RNE
  return (short)u;
}
__device__ __forceinline__ float bf2f(short s) {
  unsigned u = ((unsigned)(unsigned short)s) << 16;
  return __builtin_bit_cast(float, u);
}

// ---- P1: pack W1 seq rows into B-fragment layout [kt][ct][lane][j], bf16 ----
// k-order: 0..127 seq_items (W1 rows 128..255), 128..191 seq_cats (rows 320..383),
//          192..223 seq_times (rows 384..415), 224..255 seq_beh (rows 416..447)
__global__ void wfrag_build(const float* __restrict__ W1, short* __restrict__ Wfrag) {
  int g = blockIdx.x * 256 + threadIdx.x;          // 65536 elements
  int j = g & 7, lane = (g >> 3) & 63, ct = (g >> 9) & 15, kt = g >> 13;
  int k = kt * 32 + (lane >> 4) * 8 + j;
  int n = ct * 16 + (lane & 15);
  int row = (k < 128) ? (k + 128) : (k + 192);
  Wfrag[g] = f2bf(W1[row * HID + n]);
}

// ---- P2: base[b][n], 8 b's per block ----
__global__ void base_build(const float* __restrict__ item_emb, const float* __restrict__ cat_emb,
                           const float* __restrict__ W1, const float* __restrict__ b1,
                           float* __restrict__ base) {
  int b0 = blockIdx.x * 8;
  int tid = threadIdx.x;
  __shared__ float it[8][128];
  __shared__ float ctm[8][64];
  for (int i = tid; i < 8 * 128; i += 256) it[i >> 7][i & 127] = item_emb[(b0 + (i >> 7)) * DI + (i & 127)];
  for (int i = tid; i < 8 * 64; i += 256)  ctm[i >> 6][i & 63] = cat_emb[(b0 + (i >> 6)) * DC + (i & 63)];
  __syncthreads();
  int n = tid;
  float bv = b1[n];
  float acc[8];
#pragma unroll
  for (int i = 0; i < 8; ++i) acc[i] = bv;
  for (int d = 0; d < 128; ++d) {
    float wv = W1[d * HID + n];
#pragma unroll
    for (int i = 0; i < 8; ++i) acc[i] += it[i][d] * wv;
  }
  for (int d = 0; d < 64; ++d) {
    float wv = W1[(256 + d) * HID + n];
#pragma unroll
    for (int i = 0; i < 8; ++i) acc[i] += ctm[i][d] * wv;
  }
#pragma unroll
  for (int i = 0; i < 8; ++i) base[(b0 + i) * HID + n] = acc[i];
}

// ---- main: one block per b ----
__global__ __launch_bounds__(256) void din_main(
    const float* __restrict__ seq_items, const float* __restrict__ seq_cats,
    const float* __restrict__ seq_times, const float* __restrict__ seq_beh,
    const float* __restrict__ mask, const float* __restrict__ W2,
    const float* __restrict__ b2, const short* __restrict__ Wfrag,
    const float* __restrict__ base, float* __restrict__ out) {
  const int b = blockIdx.x;
  const int tid = threadIdx.x;
  const int w = tid >> 6;
  const int lane = tid & 63;
  const int quad = lane >> 4;
  const int l15 = lane & 15;

  __shared__ __align__(16) short A[64 * AP];   // 33.8 KB
  __shared__ float score_part[4][64];
  __shared__ float score_all[208];
  __shared__ float s_inv;

  // per-lane epilogue constants: n = w*64 + ct*16 + l15
  float base_r[4], w2_r[4];
#pragma unroll
  for (int ct = 0; ct < 4; ++ct) {
    int n = w * 64 + ct * 16 + l15;
    base_r[ct] = base[b * HID + n];
    w2_r[ct]   = W2[n];
  }
  const float b2v = b2[0];

  const float* srcI = seq_items + (size_t)b * Ssz * DI;
  const float* srcC = seq_cats  + (size_t)b * Ssz * DC;
  const float* srcT = seq_times + (size_t)b * Ssz * DT;
  const float* srcB = seq_beh   + (size_t)b * Ssz * DBh;

  float wacc = 0.f;   // per-thread (tid<192): unnormalized weighted-sum for k=tid

  for (int chunk = 0; chunk < 4; ++chunk) {
    const int s0 = chunk * 64;
    const int rows = (chunk == 3) ? 16 : 64;
    const int nrt = rows >> 4;
    __syncthreads();   // A reuse vs previous chunk's readers

    // ---- stage A: fp32 -> bf16, plain [s][k] layout ----
    {
      int cnt = rows * 32;   // items: 32 float4 per row
      for (int i = tid; i < cnt; i += 256) {
        int r = i >> 5, c = i & 31, s = s0 + r;
        float4 v = make_float4(0.f, 0.f, 0.f, 0.f);
        if (s < Ssz) v = *(const float4*)(srcI + s * DI + c * 4);
        short4 o; o.x = f2bf(v.x); o.y = f2bf(v.y); o.z = f2bf(v.z); o.w = f2bf(v.w);
        *(short4*)&A[r * AP + c * 4] = o;
      }
      cnt = rows * 16;       // cats
      for (int i = tid; i < cnt; i += 256) {
        int r = i >> 4, c = i & 15, s = s0 + r;
        float4 v = make_float4(0.f, 0.f, 0.f, 0.f);
        if (s < Ssz) v = *(const float4*)(srcC + s * DC + c * 4);
        short4 o; o.x = f2bf(v.x); o.y = f2bf(v.y); o.z = f2bf(v.z); o.w = f2bf(v.w);
        *(short4*)&A[r * AP + 128 + c * 4] = o;
      }
      cnt = rows * 8;        // times
      for (int i = tid; i < cnt; i += 256) {
        int r = i >> 3, c = i & 7, s = s0 + r;
        float4 v = make_float4(0.f, 0.f, 0.f, 0.f);
        if (s < Ssz) v = *(const float4*)(srcT + s * DT + c * 4);
        short4 o; o.x = f2bf(v.x); o.y = f2bf(v.y); o.z = f2bf(v.z); o.w = f2bf(v.w);
        *(short4*)&A[r * AP + 192 + c * 4] = o;
      }
      cnt = rows * 8;        // behaviors
      for (int i = tid; i < cnt; i += 256) {
        int r = i >> 3, c = i & 7, s = s0 + r;
        float4 v = make_float4(0.f, 0.f, 0.f, 0.f);
        if (s < Ssz) v = *(const float4*)(srcB + s * DBh + c * 4);
        short4 o; o.x = f2bf(v.x); o.y = f2bf(v.y); o.z = f2bf(v.z); o.w = f2bf(v.w);
        *(short4*)&A[r * AP + 224 + c * 4] = o;
      }
    }
    __syncthreads();

    // ---- MFMA: h[s][n] over K=256; wave w owns n in [64w, 64w+64) ----
    floatx4 acc[4][4];
#pragma unroll
    for (int rt = 0; rt < 4; ++rt)
#pragma unroll
      for (int ct = 0; ct < 4; ++ct) acc[rt][ct] = (floatx4)0.f;

#pragma unroll
    for (int kt = 0; kt < 8; ++kt) {
      short8 bfr[4];
      const short* wp = Wfrag + ((kt * 16 + w * 4) * 64 + lane) * 8;
#pragma unroll
      for (int ct = 0; ct < 4; ++ct) bfr[ct] = *(const short8*)(wp + ct * 512);
      short8 af[4];
#pragma unroll
      for (int rt = 0; rt < 4; ++rt)
        if (rt < nrt) af[rt] = *(const short8*)&A[(rt * 16 + l15) * AP + kt * 32 + quad * 8];
#pragma unroll
      for (int rt = 0; rt < 4; ++rt)
        if (rt < nrt) {
#pragma unroll
          for (int ct = 0; ct < 4; ++ct)
            acc[rt][ct] = __builtin_amdgcn_mfma_f32_16x16x32_bf16(af[rt], bfr[ct], acc[rt][ct], 0, 0, 0);
        }
    }

    // ---- epilogue: silu, dot W2 over n, cross-lane reduce ----
    // C layout: col(n_local)=lane&15, row(s_local in tile)=quad*4+reg
#pragma unroll
    for (int rt = 0; rt < 4; ++rt) {
      if (rt >= nrt) continue;
      float p[4];
#pragma unroll
      for (int reg = 0; reg < 4; ++reg) {
        float sum = 0.f;
#pragma unroll
        for (int ct = 0; ct < 4; ++ct) {
          float h = acc[rt][ct][reg] + base_r[ct];
          float sl = h / (1.f + __expf(-h));       // silu
          sum += sl * w2_r[ct];
        }
        sum += __shfl_xor(sum, 1);
        sum += __shfl_xor(sum, 2);
        sum += __shfl_xor(sum, 4);
        sum += __shfl_xor(sum, 8);
        p[reg] = sum;
      }
      if (l15 == 0) {
#pragma unroll
        for (int reg = 0; reg < 4; ++reg)
          score_part[w][rt * 16 + quad * 4 + reg] = p[reg];
      }
    }
    __syncthreads();

    // ---- combine 4 waves, sigmoid, mask -> raw score ----
    if (tid < rows) {
      float tot = score_part[0][tid] + score_part[1][tid] + score_part[2][tid] + score_part[3][tid];
      int s = s0 + tid;
      float sc = 0.f;
      if (s < Ssz) sc = mask[b * Ssz + s] / (1.f + __expf(-(tot + b2v)));
      score_all[s] = sc;
    }
    __syncthreads();

    // ---- unnormalized weighted sums from the LDS tile (k=tid: 0..127 items, 128..191 cats) ----
    if (tid < DOUT) {
#pragma unroll 8
      for (int r = 0; r < rows; ++r)
        wacc += bf2f(A[r * AP + tid]) * score_all[s0 + r];
    }
  }

  // ---- normalize ----
  if (tid < 64) {
    float ssum = score_all[tid] + score_all[tid + 64] + score_all[tid + 128];
    if (tid < 16) ssum += score_all[tid + 192];
    ssum += __shfl_xor(ssum, 1);
    ssum += __shfl_xor(ssum, 2);
    ssum += __shfl_xor(ssum, 4);
    ssum += __shfl_xor(ssum, 8);
    ssum += __shfl_xor(ssum, 16);
    ssum += __shfl_xor(ssum, 32);
    if (tid == 0) s_inv = 1.f / (ssum + 1e-8f);
  }
  __syncthreads();
  if (tid < DOUT) out[b * DOUT + tid] = wacc * s_inv;
}

extern "C" void kernel_launch(void* const* d_in, const int* in_sizes, int n_in,
                              void* d_out, int out_size, void* d_ws, size_t ws_size,
                              hipStream_t stream) {
  const float* item_emb  = (const float*)d_in[0];
  const float* cat_emb   = (const float*)d_in[1];
  const float* seq_items = (const float*)d_in[2];
  const float* seq_cats  = (const float*)d_in[3];
  const float* seq_times = (const float*)d_in[4];
  const float* seq_beh   = (const float*)d_in[5];
  const float* mask      = (const float*)d_in[6];
  const float* W1        = (const float*)d_in[7];
  const float* b1        = (const float*)d_in[8];
  const float* W2        = (const float*)d_in[9];
  const float* b2        = (const float*)d_in[10];
  float* out = (float*)d_out;

  short* Wfrag = (short*)d_ws;                                   // 65536 bf16 = 128 KB
  float* base  = (float*)((char*)d_ws + 65536 * sizeof(short));  // 2048*256 fp32 = 2 MB

  wfrag_build<<<256, 256, 0, stream>>>(W1, Wfrag);
  base_build<<<256, 256, 0, stream>>>(item_emb, cat_emb, W1, b1, base);
  din_main<<<2048, 256, 0, stream>>>(seq_items, seq_cats, seq_times, seq_beh,
                                     mask, W2, b2, Wfrag, base, out);
}

// Round 2
// 572.116 us; speedup vs baseline: 1.3047x; 1.3047x over previous
//
#include <hip/hip_runtime.h>

// DIN attention pooling, MI355X.  Round 2: parallelism restructure.
//   wfrag_build : W1 seq-rows (K=256 reordered) -> bf16 MFMA-B-fragment layout in ws
//   base_build  : base[b,h] = b1 + item_emb@W1[0:128] + cat_emb@W1[256:320]  (2048 blocks)
//   din_score   : 8192 blocks = (b, chunk of 64 s-rows). Stage fp32->bf16 LDS,
//                 MFMA h=A@Wseq(+base), silu, dot W2, sigmoid*mask -> raw score;
//                 per-chunk UNNORMALIZED weighted sums + score-sum -> ws partials
//                 (deterministic, no atomics, no zero-init).
//   din_finalize: out[b,k] = sum_c wsum[b,c,k] / (sum_c ssum[b,c] + 1e-8)
// R1 lesson: 1 block/b with 4 serial chunks was latency-bound (OCC 12%, HBM 6%).

#define Bsz  2048
#define Ssz  200
#define DI   128
#define DC   64
#define DT   32
#define DBh  32
#define HID  256
#define DOUT 192
#define AP   264   // LDS A row pitch in shorts (528 B: 16B-aligned)

using short8  = __attribute__((ext_vector_type(8))) short;
using floatx4 = __attribute__((ext_vector_type(4))) float;

__device__ __forceinline__ short f2bf(float x) {
  unsigned u = __builtin_bit_cast(unsigned, x);
  u = (u + 0x7FFFu + ((u >> 16) & 1u)) >> 16;   // RNE
  return (short)u;
}
__device__ __forceinline__ float bf2f(short s) {
  unsigned u = ((unsigned)(unsigned short)s) << 16;
  return __builtin_bit_cast(float, u);
}

// ---- pack W1 seq rows into B-fragment layout [kt][ct][lane][j], bf16 ----
// k-order: 0..127 seq_items (W1 rows 128..255), 128..191 seq_cats (rows 320..383),
//          192..223 seq_times (rows 384..415), 224..255 seq_beh (rows 416..447)
__global__ void wfrag_build(const float* __restrict__ W1, short* __restrict__ Wfrag) {
  int g = blockIdx.x * 256 + threadIdx.x;          // 65536 elements
  int j = g & 7, lane = (g >> 3) & 63, ct = (g >> 9) & 15, kt = g >> 13;
  int k = kt * 32 + (lane >> 4) * 8 + j;
  int n = ct * 16 + (lane & 15);
  int row = (k < 128) ? (k + 128) : (k + 192);
  Wfrag[g] = f2bf(W1[row * HID + n]);
}

// ---- base[b][n]: one b per block, thread = n ----
__global__ __launch_bounds__(256) void base_build(
    const float* __restrict__ item_emb, const float* __restrict__ cat_emb,
    const float* __restrict__ W1, const float* __restrict__ b1,
    float* __restrict__ base) {
  const int b = blockIdx.x;
  const int n = threadIdx.x;
  __shared__ float f[192];
  if (n < 128) f[n] = item_emb[b * DI + n];
  else if (n < 192) f[n] = cat_emb[b * DC + n - 128];
  __syncthreads();
  float acc = b1[n];
#pragma unroll 8
  for (int d = 0; d < 128; ++d) acc += f[d] * W1[d * HID + n];
#pragma unroll 8
  for (int d = 0; d < 64; ++d) acc += f[128 + d] * W1[(256 + d) * HID + n];
  base[b * HID + n] = acc;
}

// ---- main: one block per (b, chunk) ----
__global__ __launch_bounds__(256) void din_score(
    const float* __restrict__ seq_items, const float* __restrict__ seq_cats,
    const float* __restrict__ seq_times, const float* __restrict__ seq_beh,
    const float* __restrict__ mask, const float* __restrict__ W2,
    const float* __restrict__ b2, const short* __restrict__ Wfrag,
    const float* __restrict__ base, float* __restrict__ wsum_part,
    float* __restrict__ ssum_part) {
  const int bc = blockIdx.x;
  const int b = bc >> 2;
  const int chunk = bc & 3;
  const int s0 = chunk * 64;
  const int sl = (chunk == 3) ? 8 : 64;    // valid rows in this chunk
  const int tid = threadIdx.x;
  const int w = tid >> 6;
  const int lane = tid & 63;
  const int quad = lane >> 4;
  const int l15 = lane & 15;

  __shared__ __align__(16) short A[64 * AP];   // 33.8 KB
  __shared__ float score_part[4][64];
  __shared__ float score_all[64];

  // per-lane epilogue constants: n = w*64 + ct*16 + l15
  float base_r[4], w2_r[4];
#pragma unroll
  for (int ct = 0; ct < 4; ++ct) {
    int n = w * 64 + ct * 16 + l15;
    base_r[ct] = base[b * HID + n];
    w2_r[ct]   = W2[n];
  }
  const float b2v = b2[0];

  const float* srcI = seq_items + (size_t)b * Ssz * DI + (size_t)s0 * DI;
  const float* srcC = seq_cats  + (size_t)b * Ssz * DC + (size_t)s0 * DC;
  const float* srcT = seq_times + (size_t)b * Ssz * DT + (size_t)s0 * DT;
  const float* srcB = seq_beh   + (size_t)b * Ssz * DBh + (size_t)s0 * DBh;

  // ---- stage A: fp32 -> bf16, plain [s][k]; rows >= sl zero-filled ----
#pragma unroll
  for (int ii = 0; ii < 8; ++ii) {           // items: 64 rows x 32 float4
    int i = tid + ii * 256;
    int r = i >> 5, c = i & 31;
    float4 v = make_float4(0.f, 0.f, 0.f, 0.f);
    if (r < sl) v = *(const float4*)(srcI + r * DI + c * 4);
    short4 o; o.x = f2bf(v.x); o.y = f2bf(v.y); o.z = f2bf(v.z); o.w = f2bf(v.w);
    *(short4*)&A[r * AP + c * 4] = o;
  }
#pragma unroll
  for (int ii = 0; ii < 4; ++ii) {           // cats: 64 x 16 float4
    int i = tid + ii * 256;
    int r = i >> 4, c = i & 15;
    float4 v = make_float4(0.f, 0.f, 0.f, 0.f);
    if (r < sl) v = *(const float4*)(srcC + r * DC + c * 4);
    short4 o; o.x = f2bf(v.x); o.y = f2bf(v.y); o.z = f2bf(v.z); o.w = f2bf(v.w);
    *(short4*)&A[r * AP + 128 + c * 4] = o;
  }
#pragma unroll
  for (int ii = 0; ii < 2; ++ii) {           // times: 64 x 8 float4
    int i = tid + ii * 256;
    int r = i >> 3, c = i & 7;
    float4 v = make_float4(0.f, 0.f, 0.f, 0.f);
    if (r < sl) v = *(const float4*)(srcT + r * DT + c * 4);
    short4 o; o.x = f2bf(v.x); o.y = f2bf(v.y); o.z = f2bf(v.z); o.w = f2bf(v.w);
    *(short4*)&A[r * AP + 192 + c * 4] = o;
  }
#pragma unroll
  for (int ii = 0; ii < 2; ++ii) {           // behaviors: 64 x 8 float4
    int i = tid + ii * 256;
    int r = i >> 3, c = i & 7;
    float4 v = make_float4(0.f, 0.f, 0.f, 0.f);
    if (r < sl) v = *(const float4*)(srcB + r * DBh + c * 4);
    short4 o; o.x = f2bf(v.x); o.y = f2bf(v.y); o.z = f2bf(v.z); o.w = f2bf(v.w);
    *(short4*)&A[r * AP + 224 + c * 4] = o;
  }
  __syncthreads();

  // ---- MFMA: h[s][n] over K=256; wave w owns n in [64w, 64w+64) ----
  floatx4 acc[4][4];
#pragma unroll
  for (int rt = 0; rt < 4; ++rt)
#pragma unroll
    for (int ct = 0; ct < 4; ++ct) acc[rt][ct] = (floatx4)0.f;

#pragma unroll
  for (int kt = 0; kt < 8; ++kt) {
    short8 bfr[4];
    const short* wp = Wfrag + ((kt * 16 + w * 4) * 64 + lane) * 8;
#pragma unroll
    for (int ct = 0; ct < 4; ++ct) bfr[ct] = *(const short8*)(wp + ct * 512);
    short8 af[4];
#pragma unroll
    for (int rt = 0; rt < 4; ++rt)
      af[rt] = *(const short8*)&A[(rt * 16 + l15) * AP + kt * 32 + quad * 8];
#pragma unroll
    for (int rt = 0; rt < 4; ++rt)
#pragma unroll
      for (int ct = 0; ct < 4; ++ct)
        acc[rt][ct] = __builtin_amdgcn_mfma_f32_16x16x32_bf16(af[rt], bfr[ct], acc[rt][ct], 0, 0, 0);
  }

  // ---- epilogue: silu, dot W2 over n, cross-lane reduce ----
  // C layout: col(n_local)=lane&15, row(s_local in tile)=quad*4+reg
#pragma unroll
  for (int rt = 0; rt < 4; ++rt) {
    float p[4];
#pragma unroll
    for (int reg = 0; reg < 4; ++reg) {
      float sum = 0.f;
#pragma unroll
      for (int ct = 0; ct < 4; ++ct) {
        float h = acc[rt][ct][reg] + base_r[ct];
        float sli = h / (1.f + __expf(-h));       // silu
        sum += sli * w2_r[ct];
      }
      sum += __shfl_xor(sum, 1);
      sum += __shfl_xor(sum, 2);
      sum += __shfl_xor(sum, 4);
      sum += __shfl_xor(sum, 8);
      p[reg] = sum;
    }
    if (l15 == 0) {
#pragma unroll
      for (int reg = 0; reg < 4; ++reg)
        score_part[w][rt * 16 + quad * 4 + reg] = p[reg];
    }
  }
  __syncthreads();

  // ---- combine 4 waves, sigmoid, mask -> raw score; block score-sum ----
  if (tid < 64) {
    float tot = score_part[0][tid] + score_part[1][tid] + score_part[2][tid] + score_part[3][tid];
    float sc = 0.f;
    if (tid < sl) sc = mask[b * Ssz + s0 + tid] / (1.f + __expf(-(tot + b2v)));
    score_all[tid] = sc;
    float ssum = sc;
    ssum += __shfl_xor(ssum, 1);
    ssum += __shfl_xor(ssum, 2);
    ssum += __shfl_xor(ssum, 4);
    ssum += __shfl_xor(ssum, 8);
    ssum += __shfl_xor(ssum, 16);
    ssum += __shfl_xor(ssum, 32);
    if (tid == 0) ssum_part[bc] = ssum;
  }
  __syncthreads();

  // ---- unnormalized weighted sums from the LDS tile (k=tid: 0..127 items, 128..191 cats) ----
  if (tid < DOUT) {
    float wacc = 0.f;
#pragma unroll 8
    for (int r = 0; r < 64; ++r)
      wacc += bf2f(A[r * AP + tid]) * score_all[r];
    wsum_part[(size_t)bc * DOUT + tid] = wacc;
  }
}

// ---- finalize: out[b,k] = sum_c wsum / (sum_c ssum + 1e-8) ----
__global__ void din_finalize(const float* __restrict__ wsum_part,
                             const float* __restrict__ ssum_part,
                             float* __restrict__ out) {
  int t = blockIdx.x * 256 + threadIdx.x;
  if (t >= Bsz * DOUT) return;
  int b = t / DOUT, k = t - b * DOUT;
  float ss = ssum_part[b * 4] + ssum_part[b * 4 + 1] + ssum_part[b * 4 + 2] + ssum_part[b * 4 + 3];
  float ws = wsum_part[(size_t)(b * 4 + 0) * DOUT + k] + wsum_part[(size_t)(b * 4 + 1) * DOUT + k]
           + wsum_part[(size_t)(b * 4 + 2) * DOUT + k] + wsum_part[(size_t)(b * 4 + 3) * DOUT + k];
  out[t] = ws / (ss + 1e-8f);
}

extern "C" void kernel_launch(void* const* d_in, const int* in_sizes, int n_in,
                              void* d_out, int out_size, void* d_ws, size_t ws_size,
                              hipStream_t stream) {
  const float* item_emb  = (const float*)d_in[0];
  const float* cat_emb   = (const float*)d_in[1];
  const float* seq_items = (const float*)d_in[2];
  const float* seq_cats  = (const float*)d_in[3];
  const float* seq_times = (const float*)d_in[4];
  const float* seq_beh   = (const float*)d_in[5];
  const float* mask      = (const float*)d_in[6];
  const float* W1        = (const float*)d_in[7];
  const float* b1        = (const float*)d_in[8];
  const float* W2        = (const float*)d_in[9];
  const float* b2        = (const float*)d_in[10];
  float* out = (float*)d_out;

  char* ws = (char*)d_ws;
  short* Wfrag     = (short*)ws;                          // 128 KB
  float* base      = (float*)(ws + 131072);               // 2 MB
  float* wsum_part = (float*)(ws + 131072 + 2097152);     // 8192*192*4 = 6 MB
  float* ssum_part = (float*)(ws + 131072 + 2097152 + 6291456);  // 32 KB

  wfrag_build<<<256, 256, 0, stream>>>(W1, Wfrag);
  base_build<<<Bsz, 256, 0, stream>>>(item_emb, cat_emb, W1, b1, base);
  din_score<<<Bsz * 4, 256, 0, stream>>>(seq_items, seq_cats, seq_times, seq_beh,
                                         mask, W2, b2, Wfrag, base,
                                         wsum_part, ssum_part);
  din_finalize<<<(Bsz * DOUT + 255) / 256, 256, 0, stream>>>(wsum_part, ssum_part, out);
}